// Round 10
// baseline (37.967 us; speedup 1.0000x reference)
//
#include <hip/hip_runtime.h>

// Fully-fused 4-level db4 wavedec ('symmetric'), faithful to the JAX/pywt reference.
// x: [B=64, L=4096, C=32] f32. Out flat: cA4,cD4,cD3,cD2,cD1 each [B,C,len].
// lens: 4096 -> 2051 -> 1029 -> 518 -> 262.
// SINGLE-WAVE workgroups: 8192 blocks x 64 thr (2-ch group, tile of 33 cA4).
// __launch_bounds__(64) => compiler elides s_barrier (wave-internal waitcnt
// only): zero inter-wave lockstep; 13 independent waves/CU (LDS 12.2 KB/WG via
// overlaying cd2..ca4 staging into the dead x-buffer).

#define NT 64
#define NCHB 2

// Window-row pitches (floats), == 2 mod 4: b64 windows spread across bank-pairs.
#define LPX 634  // x span <= 618 (+13 margins)
#define LP1 322  // l1 span <= 306
#define LP2 166  // l2 span <= 150
#define LP3 86   // l3 span <= 72
// Output staging pitches (even).
#define CDP1 314 // cd1 span <= 306
#define CDP2 154 // cd2 span <= 150
#define CDP3 82  // cd3 span <= 72
#define CDP4 40  // cd4 span <= 33
#define CAP4 40  // ca4 span <= 33

#define L0C 4096
#define L1C 2051
#define L2C 1029
#define L3C 518
#define L4C 262
#define SC 2048

// All output offsets fit in int (out_size ~ 8.44M floats).
#define OFF_CD4 (SC * L4C)
#define OFF_CD3 (2 * SC * L4C)
#define OFF_CD2 (OFF_CD3 + SC * L3C)
#define OFF_CD1 (OFF_CD2 + SC * L2C)

__device__ __forceinline__ void filt8(
    const float w0, const float w1, const float w2, const float w3,
    const float w4, const float w5, const float w6, const float w7,
    float& a, float& d) {
    // db4 correlation kernels (dec_lo reversed = _H; dec_hi reversed), split trees.
    constexpr float FLO[8] = {
        0.23037781330885523f,  0.7148465705525415f,  0.6308807679295904f,
        -0.02798376941698385f, -0.18703481171888114f, 0.030841381835986965f,
        0.032883011666982945f, -0.010597401784997278f};
    constexpr float FHI[8] = {
        -0.010597401784997278f, -0.032883011666982945f, 0.030841381835986965f,
        0.18703481171888114f,  -0.02798376941698385f,  -0.6308807679295904f,
        0.7148465705525415f,   -0.23037781330885523f};
    float a0 = FLO[0] * w0;
    a0 = fmaf(FLO[1], w1, a0); a0 = fmaf(FLO[2], w2, a0); a0 = fmaf(FLO[3], w3, a0);
    float a1 = FLO[4] * w4;
    a1 = fmaf(FLO[5], w5, a1); a1 = fmaf(FLO[6], w6, a1); a1 = fmaf(FLO[7], w7, a1);
    a = a0 + a1;
    float d0 = FHI[0] * w0;
    d0 = fmaf(FHI[1], w1, d0); d0 = fmaf(FHI[2], w2, d0); d0 = fmaf(FHI[3], w3, d0);
    float d1 = FHI[4] * w4;
    d1 = fmaf(FHI[5], w5, d1); d1 = fmaf(FHI[6], w6, d1); d1 = fmaf(FHI[7], w7, d1);
    d = d0 + d1;
}

// One even-aligned run of R outputs (R even). Full runs tile the span exactly;
// the remainder slot does an even-clamped run (+ scalar tail if span odd);
// higher slots return immediately.
template <int R, bool MG, bool LAST>
__device__ __forceinline__ void level_run(
    const float* __restrict__ src, int PS, int srclo,
    float* __restrict__ dst, int PD, int DL,
    int lo, int hi,
    float* __restrict__ cdbuf, int CDP,
    float* __restrict__ cabuf,
    int c, int slot) {
    static_assert((R & 1) == 0, "R must be even");
    const int span = hi - lo;
    const int nrun = span / R;
    bool tail = false;
    int i0;
    if (slot < nrun) {
        i0 = lo + slot * R;
    } else if (slot == nrun && nrun * R < span) {
        i0 = lo + ((span - R) & ~1);
        tail = (span & 1) != 0;
    } else {
        return;
    }

    const float* rowb = src + c * PS;
    const float2* row2 = reinterpret_cast<const float2*>(rowb);
    const int p = i0 - (srclo >> 1);  // sample t at word t-srclo+6; first tap t=2*i0-6
    float2 f0 = row2[p], f1 = row2[p + 1], f2 = row2[p + 2];

    float* dbase = LAST ? nullptr : dst + c * PD;
    float* cdbase = cdbuf + c * CDP;
    float* cabase = LAST ? cabuf + c * CAP4 : nullptr;

    float ap = 0.f, dp = 0.f;
#pragma unroll
    for (int r = 0; r < R; ++r) {
        const float2 f3 = row2[p + 3 + r];
        const int i = i0 + r;
        float a, d;
        filt8(f0.x, f0.y, f1.x, f1.y, f2.x, f2.y, f3.x, f3.y, a, d);
        if (r & 1) {
            const int w = i - 1 - lo;  // even
            if constexpr (!LAST)
                *reinterpret_cast<float2*>(dbase + w + 6) = make_float2(ap, a);
            else
                *reinterpret_cast<float2*>(cabase + w) = make_float2(ap, a);
            *reinterpret_cast<float2*>(cdbase + w) = make_float2(dp, d);
        } else {
            ap = a; dp = d;
        }
        if constexpr (MG && !LAST) {
            // reflection margins for the next level (boundary tiles only)
            if (lo == 0 && i < 6) dbase[5 - i] = a;
            if (hi == DL && i >= DL - 7) dbase[(2 * DL - 1 - i) - lo + 6] = a;
        }
        f0 = f1; f1 = f2; f2 = f3;
    }
    if (tail) {
        const int i = hi - 1;
        const float* s = rowb + 6 - srclo;  // s[t] = sample t
        float a, d;
        filt8(s[2*i-6], s[2*i-5], s[2*i-4], s[2*i-3],
              s[2*i-2], s[2*i-1], s[2*i],   s[2*i+1], a, d);
        if constexpr (!LAST) {
            dbase[i - lo + 6] = a;
            if constexpr (MG) {
                if (hi == DL && i >= DL - 7) dbase[(2 * DL - 1 - i) - lo + 6] = a;
            }
        } else {
            cabase[i - lo] = a;
        }
        cdbase[i - lo] = d;
    }
}

// Dump staged rows to global: float2 LDS reads, coalesced dword stores.
__device__ __forceinline__ void dump_rows(
    const float* __restrict__ buf, int pitch, int bufLo,
    float* __restrict__ gbase, int rowLen, int ownLo, int ownHi, int tid) {
    const int span = ownHi - ownLo;
    const int n2 = span >> 1;
    const int off = ownLo - bufLo;
#pragma unroll
    for (int c2 = 0; c2 < NCHB; ++c2) {
        const float2* s2 = reinterpret_cast<const float2*>(buf + c2 * pitch + off);
        float* g = gbase + c2 * rowLen + ownLo;
        for (int k = tid; k < n2; k += NT) {
            const float2 v = s2[k];
            g[2 * k] = v.x;
            g[2 * k + 1] = v.y;
        }
        if ((span & 1) && tid == 0) g[span - 1] = buf[c2 * pitch + off + span - 1];
    }
}

template <bool MG>
__device__ __forceinline__ void cascade(
    const float* bx, float* b1, float* b2, float* b3,
    float* cd1, float* cd2, float* cd3, float* cd4, float* ca4,
    float* __restrict__ out, int sigB, int tile, int c, int slot, int tid,
    int lox, int lo1, int hi1, int lo2, int hi2, int lo3, int hi3,
    int lo4, int hi4) {
    // owned (exclusive, tile-partitioned) detail ranges
    const int o1lo = tile ? 264 * tile - 34 : 0;
    const int o1hi = (tile == 7) ? L1C : 264 * tile + 230;
    const int o2lo = tile ? 132 * tile - 10 : 0;
    const int o2hi = (tile == 7) ? L2C : 132 * tile + 122;
    const int o3lo = tile ? 66 * tile - 2 : 0;
    const int o3hi = (tile == 7) ? L3C : 66 * tile + 64;

    level_run<10, MG, false>(bx, LPX, lox, b1, LP1, L1C, lo1, hi1, cd1, CDP1,
                             nullptr, c, slot);
    __syncthreads();

    dump_rows(cd1, CDP1, lo1, out + OFF_CD1 + sigB * L1C, L1C, o1lo, o1hi, tid);
    level_run<6, MG, false>(b1, LP1, lo1, b2, LP2, L2C, lo2, hi2, cd2, CDP2,
                            nullptr, c, slot);
    __syncthreads();

    dump_rows(cd2, CDP2, lo2, out + OFF_CD2 + sigB * L2C, L2C, o2lo, o2hi, tid);
    level_run<4, MG, false>(b2, LP2, lo2, b3, LP3, L3C, lo3, hi3, cd3, CDP3,
                            nullptr, c, slot);
    __syncthreads();

    dump_rows(cd3, CDP3, lo3, out + OFF_CD3 + sigB * L3C, L3C, o3lo, o3hi, tid);
    level_run<2, MG, true>(b3, LP3, lo3, nullptr, 0, L4C, lo4, hi4, cd4, CDP4,
                           ca4, c, slot);
    __syncthreads();

    dump_rows(cd4, CDP4, lo4, out + OFF_CD4 + sigB * L4C, L4C, lo4, hi4, tid);
    dump_rows(ca4, CAP4, lo4, out + sigB * L4C, L4C, lo4, hi4, tid);
}

__global__ __launch_bounds__(NT, 3) void fused_dwt_kernel(
    const float* __restrict__ x, float* __restrict__ out) {
    // bx region is dead after level 1 -> overlay cd2/cd3/cd4/ca4 staging there.
    __shared__ __align__(16) float bxpool[NCHB * LPX];
    __shared__ __align__(16) float b1[NCHB * LP1];
    __shared__ __align__(16) float b2[NCHB * LP2];
    __shared__ __align__(16) float b3[NCHB * LP3];
    __shared__ __align__(16) float cd1[NCHB * CDP1];
    float* bx  = bxpool;
    float* cd2 = bxpool;                             // 2*154 = 308
    float* cd3 = bxpool + NCHB * CDP2;               // +2*82 = 472
    float* cd4 = bxpool + NCHB * (CDP2 + CDP3);      // +2*40 = 552
    float* ca4 = bxpool + NCHB * (CDP2 + CDP3 + CDP4);  // +2*40 = 632 <= 1268

    // XCD swizzle: 8192 blocks = 8 XCDs x 1024 contiguous works; the 16
    // channel-group siblings (consecutive works) share one XCD's L2.
    const int bid = blockIdx.x;
    const int work = (bid & 7) * 1024 + (bid >> 3);
    const int cg = work & 15;          // channel group 0..15 (2 ch each)
    const int tile = (work >> 4) & 7;  // cA4 tile 0..7
    const int b = work >> 7;           // batch 0..63

    const int tid = threadIdx.x;
    const int c = tid & 1;
    const int slot = tid >> 1;  // 0..31
    const int c0 = cg * 2;
    const int sigB = b * 32 + c0;

    const int lo4 = 33 * tile, hi4 = min(L4C, lo4 + 33);
    const int lo3 = max(0, 2 * lo4 - 6), hi3 = min(L3C, 2 * hi4);
    const int lo2 = max(0, 2 * lo3 - 6), hi2 = min(L2C, 2 * hi3);
    const int lo1 = max(0, 2 * lo2 - 6), hi1 = min(L1C, 2 * hi2);
    const int lox = max(0, 2 * lo1 - 6), hix = min(L0C, 2 * hi1);

    // ---- stage x tile into transposed rows: float2 covers the 2 channels;
    // float2 pair writes per row (+ reflection margins) ----
    const float* xb = x + b * (L0C * 32) + c0;
    const int npair = (hix - lox) >> 1;
    for (int q = tid; q < npair; q += NT) {
        const int j = q << 1;
        const int t = lox + j;
        const float2 va = *reinterpret_cast<const float2*>(xb + t * 32);
        const float2 vb = *reinterpret_cast<const float2*>(xb + t * 32 + 32);
        const float av[2] = {va.x, va.y};
        const float bv[2] = {vb.x, vb.y};
#pragma unroll
        for (int hh = 0; hh < NCHB; ++hh)
            *reinterpret_cast<float2*>(bx + hh * LPX + 6 + j) =
                make_float2(av[hh], bv[hh]);
        if (lox == 0 && t < 6) {
#pragma unroll
            for (int hh = 0; hh < NCHB; ++hh) {
                bx[hh * LPX + 5 - t] = av[hh];
                if (t + 1 < 6) bx[hh * LPX + 4 - t] = bv[hh];
            }
        }
        if (hix == L0C && t + 1 >= L0C - 7) {
#pragma unroll
            for (int hh = 0; hh < NCHB; ++hh) {
                if (t >= L0C - 7) bx[hh * LPX + (2 * L0C - 1 - t) - lox + 6] = av[hh];
                bx[hh * LPX + (2 * L0C - 2 - t) - lox + 6] = bv[hh];
            }
        }
    }
    __syncthreads();

    if (tile == 0 || tile == 7)
        cascade<true>(bx, b1, b2, b3, cd1, cd2, cd3, cd4, ca4, out, sigB, tile,
                      c, slot, tid, lox, lo1, hi1, lo2, hi2, lo3, hi3, lo4, hi4);
    else
        cascade<false>(bx, b1, b2, b3, cd1, cd2, cd3, cd4, ca4, out, sigB, tile,
                       c, slot, tid, lox, lo1, hi1, lo2, hi2, lo3, hi3, lo4, hi4);
}

extern "C" void kernel_launch(void* const* d_in, const int* in_sizes, int n_in,
                              void* d_out, int out_size, void* d_ws, size_t ws_size,
                              hipStream_t stream) {
    (void)in_sizes; (void)n_in; (void)d_ws; (void)ws_size; (void)out_size;
    const float* x = (const float*)d_in[0];
    float* out = (float*)d_out;
    fused_dwt_kernel<<<dim3(8192), dim3(NT), 0, stream>>>(x, out);
}

// Round 11
// 33.916 us; speedup vs baseline: 1.1195x; 1.1195x over previous
//
#include <hip/hip_runtime.h>

// 4-level db4 wavedec ('symmetric'), 2-kernel split, faithful to the reference.
// x: [B=64, L=4096, C=32] f32. Out flat: cA4,cD4,cD3,cD2,cD1 each [B,C,len].
// lens: 4096 -> 2051 -> 1029 -> 518 -> 262.
// K1: levels 1+2. Block = (batch, 4-ch group, tile of 129 cA2); 4096 x 256.
//     Writes cD1, cD2 to out; cA2 rows [sig][1032] to ws.
// K2: levels 3+4. Block = (batch, 4-ch group), full signal; 512 x 256.
//     Reads cA2 rows; writes cD3, cD4, cA4.

#define NT 256
#define NCHB 4

#define L0C 4096
#define L1C 2051
#define L2C 1029
#define L3C 518
#define L4C 262
#define SC 2048
#define WSL 1032  // ws row pitch (floats)

#define OFF_CD4 (SC * L4C)
#define OFF_CD3 (2 * SC * L4C)
#define OFF_CD2 (OFF_CD3 + SC * L3C)
#define OFF_CD1 (OFF_CD2 + SC * L2C)

// K1 LDS pitches (floats), == 2 mod 4 (pitch/2 odd -> uniform bank-pair maps).
#define PX1 550   // x span <= 534 (+13 margins = 547)
#define PB1 278   // l1 span <= 264 (+13 = 277)
#define PD1 266   // cd1 staging <= 264
#define PD2 130   // cd2 staging <= 129
#define PA2 130   // ca2 staging <= 129
// K2 LDS pitches.
#define PAS 1042  // staged cA2 row: 1029 + 13 margins
#define PB3 534   // l3 span 518 (+13 = 531)
#define PD3 522   // cd3 staging 518
#define PD4 266   // cd4 staging 262
#define PA4 266   // ca4 staging 262

__device__ __forceinline__ void filt8(
    const float w0, const float w1, const float w2, const float w3,
    const float w4, const float w5, const float w6, const float w7,
    float& a, float& d) {
    // db4 correlation kernels (dec_lo reversed = _H; dec_hi reversed), split trees.
    constexpr float FLO[8] = {
        0.23037781330885523f,  0.7148465705525415f,  0.6308807679295904f,
        -0.02798376941698385f, -0.18703481171888114f, 0.030841381835986965f,
        0.032883011666982945f, -0.010597401784997278f};
    constexpr float FHI[8] = {
        -0.010597401784997278f, -0.032883011666982945f, 0.030841381835986965f,
        0.18703481171888114f,  -0.02798376941698385f,  -0.6308807679295904f,
        0.7148465705525415f,   -0.23037781330885523f};
    float a0 = FLO[0] * w0;
    a0 = fmaf(FLO[1], w1, a0); a0 = fmaf(FLO[2], w2, a0); a0 = fmaf(FLO[3], w3, a0);
    float a1 = FLO[4] * w4;
    a1 = fmaf(FLO[5], w5, a1); a1 = fmaf(FLO[6], w6, a1); a1 = fmaf(FLO[7], w7, a1);
    a = a0 + a1;
    float d0 = FHI[0] * w0;
    d0 = fmaf(FHI[1], w1, d0); d0 = fmaf(FHI[2], w2, d0); d0 = fmaf(FHI[3], w3, d0);
    float d1 = FHI[4] * w4;
    d1 = fmaf(FHI[5], w5, d1); d1 = fmaf(FHI[6], w6, d1); d1 = fmaf(FHI[7], w7, d1);
    d = d0 + d1;
}

// One even-aligned run of R outputs (R even). Full runs tile the span; the one
// remainder slot does an even-clamped run (+ scalar tail if span odd); higher
// slots return immediately. Overlap writes are idempotent.
template <int R, bool MG, bool LAST>
__device__ __forceinline__ void level_run(
    const float* __restrict__ src, int PS, int srclo,
    float* __restrict__ dst, int PD, int DL,
    int lo, int hi,
    float* __restrict__ cdbuf, int CDP,
    float* __restrict__ cabuf, int CAP,
    int c, int slot) {
    static_assert((R & 1) == 0, "R must be even");
    const int span = hi - lo;
    const int nrun = span / R;
    bool tail = false;
    int i0;
    if (slot < nrun) {
        i0 = lo + slot * R;
    } else if (slot == nrun && nrun * R < span) {
        i0 = lo + ((span - R) & ~1);
        tail = (span & 1) != 0;
    } else {
        return;
    }

    const float* rowb = src + c * PS;
    const float2* row2 = reinterpret_cast<const float2*>(rowb);
    const int p = i0 - (srclo >> 1);  // sample t at word t-srclo+6; first tap t=2*i0-6
    float2 f0 = row2[p], f1 = row2[p + 1], f2 = row2[p + 2];

    float* dbase = LAST ? nullptr : dst + c * PD;
    float* cdbase = cdbuf + c * CDP;
    float* cabase = LAST ? cabuf + c * CAP : nullptr;

    float ap = 0.f, dp = 0.f;
#pragma unroll
    for (int r = 0; r < R; ++r) {
        const float2 f3 = row2[p + 3 + r];
        const int i = i0 + r;
        float a, d;
        filt8(f0.x, f0.y, f1.x, f1.y, f2.x, f2.y, f3.x, f3.y, a, d);
        if (r & 1) {
            const int w = i - 1 - lo;  // even
            if constexpr (!LAST)
                *reinterpret_cast<float2*>(dbase + w + 6) = make_float2(ap, a);
            else
                *reinterpret_cast<float2*>(cabase + w) = make_float2(ap, a);
            *reinterpret_cast<float2*>(cdbase + w) = make_float2(dp, d);
        } else {
            ap = a; dp = d;
        }
        if constexpr (MG && !LAST) {
            // reflection margins for the next level (boundary spans only)
            if (lo == 0 && i < 6) dbase[5 - i] = a;
            if (hi == DL && i >= DL - 7) dbase[(2 * DL - 1 - i) - lo + 6] = a;
        }
        f0 = f1; f1 = f2; f2 = f3;
    }
    if (tail) {
        const int i = hi - 1;
        const float* s = rowb + 6 - srclo;  // s[t] = sample t
        float a, d;
        filt8(s[2*i-6], s[2*i-5], s[2*i-4], s[2*i-3],
              s[2*i-2], s[2*i-1], s[2*i],   s[2*i+1], a, d);
        if constexpr (!LAST) {
            dbase[i - lo + 6] = a;
            if constexpr (MG) {
                if (hi == DL && i >= DL - 7) dbase[(2 * DL - 1 - i) - lo + 6] = a;
            }
        } else {
            cabase[i - lo] = a;
        }
        cdbase[i - lo] = d;
    }
}

// Dump staged rows to global: float2 LDS reads, coalesced dword stores.
// (ownLo - bufLo) is even at every call site.
__device__ __forceinline__ void dump_rows(
    const float* __restrict__ buf, int pitch, int bufLo,
    float* __restrict__ gbase, int rowLen, int ownLo, int ownHi, int tid) {
    const int span = ownHi - ownLo;
    const int n2 = span >> 1;
    const int off = ownLo - bufLo;
#pragma unroll
    for (int c2 = 0; c2 < NCHB; ++c2) {
        const float2* s2 = reinterpret_cast<const float2*>(buf + c2 * pitch + off);
        float* g = gbase + c2 * rowLen + ownLo;
        for (int k = tid; k < n2; k += NT) {
            const float2 v = s2[k];
            g[2 * k] = v.x;
            g[2 * k + 1] = v.y;
        }
        if ((span & 1) && tid == 0) g[span - 1] = buf[c2 * pitch + off + span - 1];
    }
}

// ------------------------- K1: levels 1 + 2 -------------------------
template <bool MG>
__device__ __forceinline__ void k1_cascade(
    const float* bx, float* b1, float* cd1, float* cd2, float* ca2,
    float* __restrict__ out, float* __restrict__ ws,
    int sigB, int tile, int c, int slot, int tid,
    int lox, int lo1, int hi1, int lo2, int hi2) {
    const int o1lo = tile ? 258 * tile : 0;
    const int o1hi = (tile == 7) ? L1C : 258 * (tile + 1);

    level_run<6, MG, false>(bx, PX1, lox, b1, PB1, L1C, lo1, hi1,
                            cd1, PD1, nullptr, 0, c, slot);
    __syncthreads();

    dump_rows(cd1, PD1, lo1, out + OFF_CD1 + sigB * L1C, L1C, o1lo, o1hi, tid);
    level_run<4, false, true>(b1, PB1, lo1, nullptr, 0, L2C, lo2, hi2,
                              cd2, PD2, ca2, PA2, c, slot);
    __syncthreads();

    dump_rows(cd2, PD2, lo2, out + OFF_CD2 + sigB * L2C, L2C, lo2, hi2, tid);
    dump_rows(ca2, PA2, lo2, ws + sigB * WSL, WSL, lo2, hi2, tid);
}

__global__ __launch_bounds__(NT) void dwt12_kernel(
    const float* __restrict__ x, float* __restrict__ out,
    float* __restrict__ ws) {
    __shared__ __align__(16) float bx[NCHB * PX1];
    __shared__ __align__(16) float b1[NCHB * PB1];
    __shared__ __align__(16) float cd1[NCHB * PD1];
    __shared__ __align__(16) float cd2[NCHB * PD2];
    __shared__ __align__(16) float ca2[NCHB * PA2];

    // XCD swizzle: 4096 blocks = 8 XCDs x 512 contiguous works.
    const int bid = blockIdx.x;
    const int work = (bid & 7) * 512 + (bid >> 3);
    const int cg = work & 7;           // channel group 0..7 (4 ch each)
    const int tile = (work >> 3) & 7;  // cA2 tile 0..7 (129 each)
    const int b = work >> 6;           // batch 0..63

    const int tid = threadIdx.x;
    const int c = tid & 3;
    const int slot = tid >> 2;  // 0..63
    const int c0 = cg * 4;
    const int sigB = b * 32 + c0;

    const int lo2 = 129 * tile, hi2 = min(L2C, lo2 + 129);
    const int lo1 = max(0, 2 * lo2 - 6), hi1 = min(L1C, 2 * hi2);
    const int lox = max(0, 2 * lo1 - 6), hix = min(L0C, 2 * hi1);

    // ---- stage x tile into transposed rows (float4 covers the 4 channels) ----
    const float* xb = x + b * (L0C * 32) + c0;
    const int npair = (hix - lox) >> 1;
    for (int q = tid; q < npair; q += NT) {
        const int j = q << 1;
        const int t = lox + j;
        const float4 va = *reinterpret_cast<const float4*>(xb + t * 32);
        const float4 vb = *reinterpret_cast<const float4*>(xb + t * 32 + 32);
        const float av[4] = {va.x, va.y, va.z, va.w};
        const float bv[4] = {vb.x, vb.y, vb.z, vb.w};
#pragma unroll
        for (int hh = 0; hh < NCHB; ++hh)
            *reinterpret_cast<float2*>(bx + hh * PX1 + 6 + j) =
                make_float2(av[hh], bv[hh]);
        if (lox == 0 && t < 6) {
#pragma unroll
            for (int hh = 0; hh < NCHB; ++hh) {
                bx[hh * PX1 + 5 - t] = av[hh];
                if (t + 1 < 6) bx[hh * PX1 + 4 - t] = bv[hh];
            }
        }
        if (hix == L0C && t + 1 >= L0C - 7) {
#pragma unroll
            for (int hh = 0; hh < NCHB; ++hh) {
                if (t >= L0C - 7) bx[hh * PX1 + (2 * L0C - 1 - t) - lox + 6] = av[hh];
                bx[hh * PX1 + (2 * L0C - 2 - t) - lox + 6] = bv[hh];
            }
        }
    }
    __syncthreads();

    if (tile == 0 || tile == 7)
        k1_cascade<true>(bx, b1, cd1, cd2, ca2, out, ws, sigB, tile, c, slot,
                         tid, lox, lo1, hi1, lo2, hi2);
    else
        k1_cascade<false>(bx, b1, cd1, cd2, ca2, out, ws, sigB, tile, c, slot,
                          tid, lox, lo1, hi1, lo2, hi2);
}

// ------------------------- K2: levels 3 + 4 -------------------------
__global__ __launch_bounds__(NT) void dwt34_kernel(
    const float* __restrict__ ws, float* __restrict__ out) {
    __shared__ __align__(16) float bA[NCHB * PAS];  // staged cA2 rows
    __shared__ __align__(16) float b3[NCHB * PB3];
    __shared__ __align__(16) float cd3[NCHB * PD3];
    __shared__ __align__(16) float cd4[NCHB * PD4];
    __shared__ __align__(16) float ca4[NCHB * PA4];

    // XCD swizzle: 512 blocks = 8 XCDs x 64 contiguous works.
    const int bid = blockIdx.x;
    const int work = (bid & 7) * 64 + (bid >> 3);
    const int cg = work & 7;   // channel group 0..7
    const int b = work >> 3;   // batch 0..63

    const int tid = threadIdx.x;
    const int c = tid & 3;
    const int slot = tid >> 2;  // 0..63
    const int sigB = b * 32 + cg * 4;

    // ---- stage cA2 rows (dense row reads) + reflection margins ----
    const float* wbase = ws + sigB * WSL;
#pragma unroll
    for (int c2 = 0; c2 < NCHB; ++c2) {
        const float2* s2 = reinterpret_cast<const float2*>(wbase + c2 * WSL);
        float* row = bA + c2 * PAS;
        for (int k = tid; k < 514; k += NT) {  // samples 0..1027
            const float2 v = s2[k];
            const int t = 2 * k;
            *reinterpret_cast<float2*>(row + t + 6) = v;
            if (t < 6) {
                row[5 - t] = v.x;
                if (t + 1 < 6) row[4 - t] = v.y;
            }
            if (t + 1 >= L2C - 7) {  // right reflection: sample s>=L2C at word (2*L2C-1-s)+6
                if (t >= L2C - 7) row[(2 * L2C - 1 - t) + 6] = v.x;
                row[(2 * L2C - 2 - t) + 6] = v.y;
            }
        }
        if (tid == 0) {  // sample 1028 (last, odd count)
            const float v = wbase[c2 * WSL + (L2C - 1)];
            row[(L2C - 1) + 6] = v;
            row[(2 * L2C - 1 - (L2C - 1)) + 6] = v;  // == row[L2C+6]
        }
    }
    __syncthreads();

    level_run<10, true, false>(bA, PAS, 0, b3, PB3, L3C, 0, L3C,
                               cd3, PD3, nullptr, 0, c, slot);
    __syncthreads();

    dump_rows(cd3, PD3, 0, out + OFF_CD3 + sigB * L3C, L3C, 0, L3C, tid);
    level_run<6, false, true>(b3, PB3, 0, nullptr, 0, L4C, 0, L4C,
                              cd4, PD4, ca4, PA4, c, slot);
    __syncthreads();

    dump_rows(cd4, PD4, 0, out + OFF_CD4 + sigB * L4C, L4C, 0, L4C, tid);
    dump_rows(ca4, PA4, 0, out + sigB * L4C, L4C, 0, L4C, tid);
}

extern "C" void kernel_launch(void* const* d_in, const int* in_sizes, int n_in,
                              void* d_out, int out_size, void* d_ws, size_t ws_size,
                              hipStream_t stream) {
    (void)in_sizes; (void)n_in; (void)ws_size; (void)out_size;
    const float* x = (const float*)d_in[0];
    float* out = (float*)d_out;
    float* ws = (float*)d_ws;
    dwt12_kernel<<<dim3(4096), dim3(NT), 0, stream>>>(x, out, ws);
    dwt34_kernel<<<dim3(512), dim3(NT), 0, stream>>>(ws, out);
}

// Round 12
// 32.322 us; speedup vs baseline: 1.1747x; 1.0493x over previous
//
#include <hip/hip_runtime.h>

// Fully-fused 4-level db4 wavedec ('symmetric'), software-pipelined phases.
// x: [B=64, L=4096, C=32] f32. Out flat: cA4,cD4,cD3,cD2,cD1 each [B,C,len].
// lens: 4096 -> 2051 -> 1029 -> 518 -> 262.
// Block = (batch, 4-ch group, tile of 33 cA4); 4096 blocks x 256 thr.
// vs r9: each level's output range is split A/B; phases co-schedule
// independent halves of ADJACENT levels (P2 = L1B + L2A, P3 = dump(cd1) +
// L2B + L3A, ...) so each barrier-delimited phase carries two independent
// DS/VALU streams + a VMEM dump stream -> 2x ILP per phase, same work.

#define NT 256
#define NCHB 4

// Window-row pitches (floats), == 2 mod 4 (pitch/2 odd): b64 accesses spread
// across bank-pairs uniformly.
#define LPX 634  // x span <= 618 (+13 margins)
#define LP1 322  // l1 span <= 306
#define LP2 166  // l2 span <= 150
#define LP3 86   // l3 span <= 72
// Output staging pitches (even).
#define CDP1 314 // cd1 span <= 306
#define CDP2 154 // cd2 span <= 150
#define CDP3 82  // cd3 span <= 78
#define CDP4 40  // cd4 span <= 33
#define CAP4 40  // ca4 span <= 33

#define L0C 4096
#define L1C 2051
#define L2C 1029
#define L3C 518
#define L4C 262
#define SC 2048

// All output offsets fit in int (out_size ~ 8.44M floats).
#define OFF_CD4 (SC * L4C)
#define OFF_CD3 (2 * SC * L4C)
#define OFF_CD2 (OFF_CD3 + SC * L3C)
#define OFF_CD1 (OFF_CD2 + SC * L2C)

// A-half sizes (even; sized so each A-half depends only on producer's A-half):
// L2A max-tap 2*lo2+143 < lo1+154 = 2*lo2+148 OK ; L3A: 2*lo3+63 < 2*lo3+66 OK ;
// L4A: 2*lo4+23 < 2*lo4+26 OK.
#define K1A 154
#define K2A 72
#define K3A 32
#define K4A 12

__device__ __forceinline__ void filt8(
    const float w0, const float w1, const float w2, const float w3,
    const float w4, const float w5, const float w6, const float w7,
    float& a, float& d) {
    // db4 correlation kernels (dec_lo reversed = _H; dec_hi reversed), split trees.
    constexpr float FLO[8] = {
        0.23037781330885523f,  0.7148465705525415f,  0.6308807679295904f,
        -0.02798376941698385f, -0.18703481171888114f, 0.030841381835986965f,
        0.032883011666982945f, -0.010597401784997278f};
    constexpr float FHI[8] = {
        -0.010597401784997278f, -0.032883011666982945f, 0.030841381835986965f,
        0.18703481171888114f,  -0.02798376941698385f,  -0.6308807679295904f,
        0.7148465705525415f,   -0.23037781330885523f};
    float a0 = FLO[0] * w0;
    a0 = fmaf(FLO[1], w1, a0); a0 = fmaf(FLO[2], w2, a0); a0 = fmaf(FLO[3], w3, a0);
    float a1 = FLO[4] * w4;
    a1 = fmaf(FLO[5], w5, a1); a1 = fmaf(FLO[6], w6, a1); a1 = fmaf(FLO[7], w7, a1);
    a = a0 + a1;
    float d0 = FHI[0] * w0;
    d0 = fmaf(FHI[1], w1, d0); d0 = fmaf(FHI[2], w2, d0); d0 = fmaf(FHI[3], w3, d0);
    float d1 = FHI[4] * w4;
    d1 = fmaf(FHI[5], w5, d1); d1 = fmaf(FHI[6], w6, d1); d1 = fmaf(FHI[7], w7, d1);
    d = d0 + d1;
}

// One even-aligned run of R outputs over sub-range [lo,hi). loF = full-level
// base (staging/dst offsets). Full runs tile the span; the remainder slot does
// an even-clamped run (+ scalar tail if span odd); higher slots return.
template <int R, bool MG, bool LAST>
__device__ __forceinline__ void level_run(
    const float* __restrict__ src, int PS, int srclo,
    float* __restrict__ dst, int PD, int DL,
    int lo, int hi, int loF,
    float* __restrict__ cdbuf, int CDP,
    float* __restrict__ cabuf, int CAP,
    int c, int slot) {
    static_assert((R & 1) == 0, "R must be even");
    const int span = hi - lo;
    const int nrun = span / R;
    bool tail = false;
    int i0;
    if (slot < nrun) {
        i0 = lo + slot * R;
    } else if (slot == nrun && nrun * R < span) {
        i0 = lo + ((span - R) & ~1);
        tail = (span & 1) != 0;
    } else {
        return;
    }

    const float* rowb = src + c * PS;
    const float2* row2 = reinterpret_cast<const float2*>(rowb);
    const int p = i0 - (srclo >> 1);  // sample t at word t-srclo+6; first tap t=2*i0-6
    float2 f0 = row2[p], f1 = row2[p + 1], f2 = row2[p + 2];

    float* dbase = LAST ? nullptr : dst + c * PD;
    float* cdbase = cdbuf + c * CDP;
    float* cabase = LAST ? cabuf + c * CAP : nullptr;

    float ap = 0.f, dp = 0.f;
#pragma unroll
    for (int r = 0; r < R; ++r) {
        const float2 f3 = row2[p + 3 + r];
        const int i = i0 + r;
        float a, d;
        filt8(f0.x, f0.y, f1.x, f1.y, f2.x, f2.y, f3.x, f3.y, a, d);
        if (r & 1) {
            const int w = i - 1 - loF;  // even
            if constexpr (!LAST)
                *reinterpret_cast<float2*>(dbase + w + 6) = make_float2(ap, a);
            else
                *reinterpret_cast<float2*>(cabase + w) = make_float2(ap, a);
            *reinterpret_cast<float2*>(cdbase + w) = make_float2(dp, d);
        } else {
            ap = a; dp = d;
        }
        if constexpr (MG && !LAST) {
            // reflection margins for the next level (boundary tiles/halves only)
            if (loF == 0 && i < 6) dbase[5 - i] = a;
            if (hi == DL && i >= DL - 7) dbase[(2 * DL - 1 - i) - loF + 6] = a;
        }
        f0 = f1; f1 = f2; f2 = f3;
    }
    if (tail) {
        const int i = hi - 1;
        const float* s = rowb + 6 - srclo;  // s[t] = sample t
        float a, d;
        filt8(s[2*i-6], s[2*i-5], s[2*i-4], s[2*i-3],
              s[2*i-2], s[2*i-1], s[2*i],   s[2*i+1], a, d);
        if constexpr (!LAST) {
            dbase[i - loF + 6] = a;
            if constexpr (MG) {
                if (hi == DL && i >= DL - 7) dbase[(2 * DL - 1 - i) - loF + 6] = a;
            }
        } else {
            cabase[i - loF] = a;
        }
        cdbase[i - loF] = d;
    }
}

// Dump staged rows to global: float2 LDS reads, coalesced dword stores.
// (ownLo - bufLo) is even at every call site.
__device__ __forceinline__ void dump_rows(
    const float* __restrict__ buf, int pitch, int bufLo,
    float* __restrict__ gbase, int rowLen, int ownLo, int ownHi, int tid) {
    const int span = ownHi - ownLo;
    const int n2 = span >> 1;
    const int off = ownLo - bufLo;
#pragma unroll
    for (int c2 = 0; c2 < NCHB; ++c2) {
        const float2* s2 = reinterpret_cast<const float2*>(buf + c2 * pitch + off);
        float* g = gbase + c2 * rowLen + ownLo;
        for (int k = tid; k < n2; k += NT) {
            const float2 v = s2[k];
            g[2 * k] = v.x;
            g[2 * k + 1] = v.y;
        }
        if ((span & 1) && tid == 0) g[span - 1] = buf[c2 * pitch + off + span - 1];
    }
}

template <bool MG>
__device__ __forceinline__ void cascade(
    const float* bx, float* b1, float* b2, float* b3,
    float* cd1, float* cd2, float* cd3, float* cd4, float* ca4,
    float* __restrict__ out, int sigB, int tile, int c, int slot, int tid,
    int lox, int lo1, int hi1, int lo2, int hi2, int lo3, int hi3,
    int lo4, int hi4) {
    // owned (exclusive, tile-partitioned) detail ranges
    const int o1lo = tile ? 264 * tile - 34 : 0;
    const int o1hi = (tile == 7) ? L1C : 264 * tile + 230;
    const int o2lo = tile ? 132 * tile - 10 : 0;
    const int o2hi = (tile == 7) ? L2C : 132 * tile + 122;
    const int o3lo = tile ? 66 * tile - 2 : 0;
    const int o3hi = (tile == 7) ? L3C : 66 * tile + 64;

    // P1: L1 first half
    level_run<4, MG, false>(bx, LPX, lox, b1, LP1, L1C, lo1, lo1 + K1A, lo1,
                            cd1, CDP1, nullptr, 0, c, slot);
    __syncthreads();

    // P2: L1 second half || L2 first half (independent streams)
    level_run<4, MG, false>(bx, LPX, lox, b1, LP1, L1C, lo1 + K1A, hi1, lo1,
                            cd1, CDP1, nullptr, 0, c, slot);
    level_run<2, MG, false>(b1, LP1, lo1, b2, LP2, L2C, lo2, lo2 + K2A, lo2,
                            cd2, CDP2, nullptr, 0, c, slot);
    __syncthreads();

    // P3: dump cd1 || L2 second half || L3 first half
    dump_rows(cd1, CDP1, lo1, out + OFF_CD1 + sigB * L1C, L1C, o1lo, o1hi, tid);
    level_run<2, MG, false>(b1, LP1, lo1, b2, LP2, L2C, lo2 + K2A, hi2, lo2,
                            cd2, CDP2, nullptr, 0, c, slot);
    level_run<2, MG, false>(b2, LP2, lo2, b3, LP3, L3C, lo3, lo3 + K3A, lo3,
                            cd3, CDP3, nullptr, 0, c, slot);
    __syncthreads();

    // P4: dump cd2 || L3 second half || L4 first half
    dump_rows(cd2, CDP2, lo2, out + OFF_CD2 + sigB * L2C, L2C, o2lo, o2hi, tid);
    level_run<2, MG, false>(b2, LP2, lo2, b3, LP3, L3C, lo3 + K3A, hi3, lo3,
                            cd3, CDP3, nullptr, 0, c, slot);
    level_run<2, false, true>(b3, LP3, lo3, nullptr, 0, L4C, lo4, lo4 + K4A, lo4,
                              cd4, CDP4, ca4, CAP4, c, slot);
    __syncthreads();

    // P5: dump cd3 || L4 second half
    dump_rows(cd3, CDP3, lo3, out + OFF_CD3 + sigB * L3C, L3C, o3lo, o3hi, tid);
    level_run<2, false, true>(b3, LP3, lo3, nullptr, 0, L4C, lo4 + K4A, hi4, lo4,
                              cd4, CDP4, ca4, CAP4, c, slot);
    __syncthreads();

    // P6: terminal dumps (no barrier after)
    dump_rows(cd4, CDP4, lo4, out + OFF_CD4 + sigB * L4C, L4C, lo4, hi4, tid);
    dump_rows(ca4, CAP4, lo4, out + sigB * L4C, L4C, lo4, hi4, tid);
}

__global__ __launch_bounds__(NT, 5) void fused_dwt_kernel(
    const float* __restrict__ x, float* __restrict__ out) {
    __shared__ __align__(16) float bx[NCHB * LPX];
    __shared__ __align__(16) float b1[NCHB * LP1];
    __shared__ __align__(16) float b2[NCHB * LP2];
    __shared__ __align__(16) float b3[NCHB * LP3];
    __shared__ __align__(16) float cd1[NCHB * CDP1];
    __shared__ __align__(16) float cd2[NCHB * CDP2];
    __shared__ __align__(16) float cd3[NCHB * CDP3];
    __shared__ __align__(16) float cd4[NCHB * CDP4];
    __shared__ __align__(16) float ca4[NCHB * CAP4];

    // XCD swizzle: 4096 blocks = 8 XCDs x 512 contiguous works; the 8
    // channel-group siblings (consecutive works) share one XCD's L2.
    const int bid = blockIdx.x;
    const int work = (bid & 7) * 512 + (bid >> 3);
    const int cg = work & 7;           // channel group 0..7 (4 ch each)
    const int tile = (work >> 3) & 7;  // cA4 tile 0..7
    const int b = work >> 6;           // batch 0..63

    const int tid = threadIdx.x;
    const int c = tid & 3;
    const int slot = tid >> 2;  // 0..63
    const int c0 = cg * 4;
    const int sigB = b * 32 + c0;

    const int lo4 = 33 * tile, hi4 = min(L4C, lo4 + 33);
    const int lo3 = max(0, 2 * lo4 - 6), hi3 = min(L3C, 2 * hi4);
    const int lo2 = max(0, 2 * lo3 - 6), hi2 = min(L2C, 2 * hi3);
    const int lo1 = max(0, 2 * lo2 - 6), hi1 = min(L1C, 2 * hi2);
    const int lox = max(0, 2 * lo1 - 6), hix = min(L0C, 2 * hi1);

    // ---- stage x tile into transposed rows: one float4 covers the block's 4
    // channels; float2 pair writes per row (+ reflection margins) ----
    const float* xb = x + b * (L0C * 32) + c0;
    const int npair = (hix - lox) >> 1;
    for (int q = tid; q < npair; q += NT) {
        const int j = q << 1;
        const int t = lox + j;
        const float4 va = *reinterpret_cast<const float4*>(xb + t * 32);
        const float4 vb = *reinterpret_cast<const float4*>(xb + t * 32 + 32);
        const float av[4] = {va.x, va.y, va.z, va.w};
        const float bv[4] = {vb.x, vb.y, vb.z, vb.w};
#pragma unroll
        for (int hh = 0; hh < NCHB; ++hh)
            *reinterpret_cast<float2*>(bx + hh * LPX + 6 + j) =
                make_float2(av[hh], bv[hh]);
        if (lox == 0 && t < 6) {
#pragma unroll
            for (int hh = 0; hh < NCHB; ++hh) {
                bx[hh * LPX + 5 - t] = av[hh];
                if (t + 1 < 6) bx[hh * LPX + 4 - t] = bv[hh];
            }
        }
        if (hix == L0C && t + 1 >= L0C - 7) {
#pragma unroll
            for (int hh = 0; hh < NCHB; ++hh) {
                if (t >= L0C - 7) bx[hh * LPX + (2 * L0C - 1 - t) - lox + 6] = av[hh];
                bx[hh * LPX + (2 * L0C - 2 - t) - lox + 6] = bv[hh];
            }
        }
    }
    __syncthreads();

    if (tile == 0 || tile == 7)
        cascade<true>(bx, b1, b2, b3, cd1, cd2, cd3, cd4, ca4, out, sigB, tile,
                      c, slot, tid, lox, lo1, hi1, lo2, hi2, lo3, hi3, lo4, hi4);
    else
        cascade<false>(bx, b1, b2, b3, cd1, cd2, cd3, cd4, ca4, out, sigB, tile,
                       c, slot, tid, lox, lo1, hi1, lo2, hi2, lo3, hi3, lo4, hi4);
}

extern "C" void kernel_launch(void* const* d_in, const int* in_sizes, int n_in,
                              void* d_out, int out_size, void* d_ws, size_t ws_size,
                              hipStream_t stream) {
    (void)in_sizes; (void)n_in; (void)d_ws; (void)ws_size; (void)out_size;
    const float* x = (const float*)d_in[0];
    float* out = (float*)d_out;
    fused_dwt_kernel<<<dim3(4096), dim3(NT), 0, stream>>>(x, out);
}